// Round 8
// baseline (82.141 us; speedup 1.0000x reference)
//
#include <hip/hip_runtime.h>
#include <hip/hip_bf16.h>
#include <cstdint>

// Problem constants (from reference): L=12, B=8192, D=1024, K=64
#define NL 12
#define NB 8192
#define ND 1024
#define NK 64
#define TB 16   // b-rows per block

typedef __attribute__((ext_vector_type(8))) short bf16x8;
typedef __attribute__((ext_vector_type(4))) float f32x4;

__device__ __forceinline__ unsigned short f2bf(float f) {
  union { float f; unsigned int u; } v; v.f = f;
  unsigned int u = v.u;
  u += 0x7FFFu + ((u >> 16) & 1u);   // round-to-nearest-even
  return (unsigned short)(u >> 16);
}

// ------------------------------------------------- fused mean+GEMM+tanh
// Single kernel (no wconv dispatch). Phase 1 = R2's proven streaming loop.
// W fp32 loads are issued AFTER phase 1 (fence: R5 spill lesson) but BEFORE
// the barrier (R7 tail-hiding lesson), in two 8-fragment chunks so peak
// VGPR stays ~110 < 128 cap. Phase 2 is pure LDS+MFMA.
__global__ void __launch_bounds__(512, 4)
fused_mean_gemm_tanh(const float* __restrict__ x,
                     const float* __restrict__ W,
                     const float* __restrict__ bias, float* __restrict__ out) {
  // xm tile: [TB][1024] bf16, row stride 2048 B, XOR-swizzled (T2)
  __shared__ __align__(16) unsigned char xs[TB * 2048];   // 32 KB
  __shared__ f32x4 pred[4 * 64];                          // 4 KB partials

  const int tid = threadIdx.x;
  const int b0 = blockIdx.x * TB;

  // -------- Phase 1: xm = sum_l x[l, b0+i, :]  (HBM-bound, NT loads) ------
  // 512 threads cover 2 rows per sweep; 8 sweeps.  (identical to R2)
  const int rhalf = tid >> 8;        // 0/1 -> which row of the pair
  const int t     = tid & 255;       // float4 index within the row
  const f32x4* x4 = (const f32x4*)x;

  for (int s = 0; s < 8; ++s) {
    const int i = 2 * s + rhalf;
    const f32x4* p = x4 + (size_t)(b0 + i) * (ND / 4) + t;
    f32x4 a = __builtin_nontemporal_load(p);
#pragma unroll
    for (int l = 1; l < NL; ++l) {
      f32x4 v = __builtin_nontemporal_load(p + (size_t)l * (NB * (ND / 4)));
      a += v;
    }
    unsigned int lo = (unsigned)f2bf(a[0]) | ((unsigned)f2bf(a[1]) << 16);
    unsigned int hi = (unsigned)f2bf(a[2]) | ((unsigned)f2bf(a[3]) << 16);
    int byte = i * 2048 + t * 8;
    byte ^= (i & 7) << 4;            // T2 XOR swizzle
    uint2 u; u.x = lo; u.y = hi;
    *(uint2*)(xs + byte) = u;
  }

  // Fence: W loads must not hoist above phase 1 (R5 post-mortem: wfrag
  // live across the streaming loop -> spill under the 128-VGPR cap).
  asm volatile("" ::: "memory");
  __builtin_amdgcn_sched_barrier(0);

  // -------- W slice: fp32 -> bf16 fragments, pre-barrier (tail-hiding) ----
  const int lane  = tid & 63;
  const int w     = tid >> 6;     // wave id
  const int ktile = w & 3;        // k-tile (16 outputs)
  const int khalf = w >> 2;       // K-dim half
  const int mn    = lane & 15;    // A: b-row | B: W-row (k) | D: col (k)
  const int g     = lane >> 4;    // k-group within fragment
  const int kn0   = ktile * 16;

  bf16x8 wfrag[16];
  const float* Wrow = W + (size_t)(kn0 + mn) * ND + khalf * 512;
#pragma unroll
  for (int chunk = 0; chunk < 2; ++chunk) {
    float4 wv[16];                 // 8 fragments x 2 float4 = 64 VGPRs
#pragma unroll
    for (int ss = 0; ss < 8; ++ss) {
      const float* wp = Wrow + 32 * (chunk * 8 + ss) + 8 * g;
      wv[2 * ss]     = *(const float4*)(wp);
      wv[2 * ss + 1] = *(const float4*)(wp + 4);
    }
#pragma unroll
    for (int ss = 0; ss < 8; ++ss) {
      bf16x8 f;
      f[0] = (short)f2bf(wv[2 * ss].x);     f[1] = (short)f2bf(wv[2 * ss].y);
      f[2] = (short)f2bf(wv[2 * ss].z);     f[3] = (short)f2bf(wv[2 * ss].w);
      f[4] = (short)f2bf(wv[2 * ss + 1].x); f[5] = (short)f2bf(wv[2 * ss + 1].y);
      f[6] = (short)f2bf(wv[2 * ss + 1].z); f[7] = (short)f2bf(wv[2 * ss + 1].w);
      wfrag[chunk * 8 + ss] = f;
    }
    __builtin_amdgcn_sched_barrier(0);   // serialize chunks: cap peak VGPR
  }
  const float bv = bias[kn0 + mn];
  __builtin_amdgcn_sched_barrier(0);     // don't sink past the barrier
  __syncthreads();

  // -------- Phase 2: out[b0+m][k] = tanh(dot/12 + bias), pure LDS+MFMA ----
  f32x4 acc = {0.f, 0.f, 0.f, 0.f};
  const int abase = mn * 2048 + 16 * g;
  const int axor  = (mn & 7) << 4;

#pragma unroll
  for (int ss = 0; ss < 16; ++ss) {
    const int step = khalf * 16 + ss;
    int byte = (abase + 64 * step) ^ axor;
    bf16x8 afrag = *(const bf16x8*)(xs + byte);        // ds_read_b128
    acc = __builtin_amdgcn_mfma_f32_16x16x32_bf16(afrag, wfrag[ss], acc, 0, 0, 0);
  }

  if (w >= 4) pred[(w - 4) * 64 + lane] = acc;
  __syncthreads();

  if (w < 4) {
    f32x4 o = pred[w * 64 + lane];
    acc += o;
    // C/D layout (m89-verified): col = lane&15, row = 4*(lane>>4) + reg
#pragma unroll
    for (int r = 0; r < 4; ++r) {
      int row = 4 * g + r;
      float val = tanhf(acc[r] * (1.0f / 12.0f) + bv);
      out[(size_t)(b0 + row) * NK + kn0 + mn] = val;
    }
  }
}

extern "C" void kernel_launch(void* const* d_in, const int* in_sizes, int n_in,
                              void* d_out, int out_size, void* d_ws, size_t ws_size,
                              hipStream_t stream) {
  const float* x    = (const float*)d_in[0];
  const float* W    = (const float*)d_in[1];
  const float* bias = (const float*)d_in[2];
  float* out = (float*)d_out;

  hipLaunchKernelGGL(fused_mean_gemm_tanh, dim3(NB / TB), dim3(512), 0, stream,
                     x, W, bias, out);
}

// Round 9
// 71.299 us; speedup vs baseline: 1.1521x; 1.1521x over previous
//
#include <hip/hip_runtime.h>
#include <hip/hip_bf16.h>
#include <cstdint>

// Problem constants (from reference): L=12, B=8192, D=1024, K=64
#define NL 12
#define NB 8192
#define ND 1024
#define NK 64
#define TB 16   // b-rows per block

typedef __attribute__((ext_vector_type(8))) short bf16x8;
typedef __attribute__((ext_vector_type(4))) float f32x4;

__device__ __forceinline__ unsigned short f2bf(float f) {
  union { float f; unsigned int u; } v; v.f = f;
  unsigned int u = v.u;
  u += 0x7FFFu + ((u >> 16) & 1u);   // round-to-nearest-even
  return (unsigned short)(u >> 16);
}

// ---------------------------------------------------------------- W -> bf16
__global__ void __launch_bounds__(256)
wconv_kernel(const float* __restrict__ W, uint2* __restrict__ Wb) {
  int i = blockIdx.x * 256 + threadIdx.x;          // 16384 float4s
  f32x4 v = *((const f32x4*)W + i);
  uint2 u;
  u.x = (unsigned)f2bf(v[0]) | ((unsigned)f2bf(v[1]) << 16);
  u.y = (unsigned)f2bf(v[2]) | ((unsigned)f2bf(v[3]) << 16);
  Wb[i] = u;
}

// ------------------------------------------------- fused mean+GEMM+tanh
// R7 champion (71.15 us). R2 structure + tail-hiding: all 16 Wb fragment
// loads are issued between the end of phase 1 and the barrier, so their
// L2 BW/latency hides under the barrier wait instead of being an exposed
// all-blocks-at-once tail. wfrag (64 VGPR) is never live during the
// 12-deep streaming batches (R5 lesson), so peak VGPR stays < 128.
// Inlining W as fp32 into this kernel was tried 3x (R3/R5/R8): always
// worse (+1.1/+14/+11 us) -> the bf16 wconv split is structural.
__global__ void __launch_bounds__(512, 4)
fused_mean_gemm_tanh(const float* __restrict__ x,
                     const unsigned short* __restrict__ Wb,
                     const float* __restrict__ bias, float* __restrict__ out) {
  // xm tile: [TB][1024] bf16, row stride 2048 B, XOR-swizzled (T2)
  __shared__ __align__(16) unsigned char xs[TB * 2048];   // 32 KB
  __shared__ f32x4 pred[4 * 64];                          // 4 KB partials

  const int tid = threadIdx.x;
  const int b0 = blockIdx.x * TB;

  // -------- Phase 1: xm = sum_l x[l, b0+i, :]  (HBM-bound, NT loads) ------
  // 512 threads cover 2 rows per sweep; 8 sweeps.
  const int rhalf = tid >> 8;        // 0/1 -> which row of the pair
  const int t     = tid & 255;       // float4 index within the row
  const f32x4* x4 = (const f32x4*)x;

  for (int s = 0; s < 8; ++s) {
    const int i = 2 * s + rhalf;
    const f32x4* p = x4 + (size_t)(b0 + i) * (ND / 4) + t;
    f32x4 a = __builtin_nontemporal_load(p);
#pragma unroll
    for (int l = 1; l < NL; ++l) {
      f32x4 v = __builtin_nontemporal_load(p + (size_t)l * (NB * (ND / 4)));
      a += v;
    }
    unsigned int lo = (unsigned)f2bf(a[0]) | ((unsigned)f2bf(a[1]) << 16);
    unsigned int hi = (unsigned)f2bf(a[2]) | ((unsigned)f2bf(a[3]) << 16);
    int byte = i * 2048 + t * 8;
    byte ^= (i & 7) << 4;            // T2 XOR swizzle
    uint2 u; u.x = lo; u.y = hi;
    *(uint2*)(xs + byte) = u;
  }

  // -------- Wb prefetch: issue BEFORE the barrier, consume after ----------
  const int lane  = tid & 63;
  const int w     = tid >> 6;     // wave id
  const int ktile = w & 3;        // k-tile (16 outputs)
  const int khalf = w >> 2;       // K-dim half
  const int mn    = lane & 15;    // A: b-row | B: W-row (k) | D: col (k)
  const int g     = lane >> 4;    // k-group within fragment
  const int kn0   = ktile * 16;

  bf16x8 wfrag[16];
  {
    const unsigned short* Wrow = Wb + (size_t)(kn0 + mn) * ND + khalf * 512;
#pragma unroll
    for (int ss = 0; ss < 16; ++ss)
      wfrag[ss] = *(const bf16x8*)(Wrow + 32 * ss + 8 * g);
  }
  const float bv = bias[kn0 + mn];
  __builtin_amdgcn_sched_barrier(0);   // don't sink the prefetch past the barrier
  __syncthreads();

  // -------- Phase 2: out[b0+m][k] = tanh(dot/12 + bias), pure LDS+MFMA ----
  f32x4 acc = {0.f, 0.f, 0.f, 0.f};
  const int abase = mn * 2048 + 16 * g;
  const int axor  = (mn & 7) << 4;

#pragma unroll
  for (int ss = 0; ss < 16; ++ss) {
    const int step = khalf * 16 + ss;
    int byte = (abase + 64 * step) ^ axor;
    bf16x8 afrag = *(const bf16x8*)(xs + byte);        // ds_read_b128
    acc = __builtin_amdgcn_mfma_f32_16x16x32_bf16(afrag, wfrag[ss], acc, 0, 0, 0);
  }

  if (w >= 4) pred[(w - 4) * 64 + lane] = acc;
  __syncthreads();

  if (w < 4) {
    f32x4 o = pred[w * 64 + lane];
    acc += o;
    // C/D layout (m89-verified): col = lane&15, row = 4*(lane>>4) + reg
#pragma unroll
    for (int r = 0; r < 4; ++r) {
      int row = 4 * g + r;
      float val = tanhf(acc[r] * (1.0f / 12.0f) + bv);
      out[(size_t)(b0 + row) * NK + kn0 + mn] = val;
    }
  }
}

extern "C" void kernel_launch(void* const* d_in, const int* in_sizes, int n_in,
                              void* d_out, int out_size, void* d_ws, size_t ws_size,
                              hipStream_t stream) {
  const float* x    = (const float*)d_in[0];
  const float* W    = (const float*)d_in[1];
  const float* bias = (const float*)d_in[2];
  float* out = (float*)d_out;
  unsigned short* Wb = (unsigned short*)d_ws;   // 64*1024 bf16 = 128 KB

  hipLaunchKernelGGL(wconv_kernel, dim3(NK * ND / 4 / 256), dim3(256), 0,
                     stream, W, (uint2*)Wb);
  hipLaunchKernelGGL(fused_mean_gemm_tanh, dim3(NB / TB), dim3(512), 0, stream,
                     x, Wb, bias, out);
}